// Round 5
// baseline (304.988 us; speedup 1.0000x reference)
//
#include <hip/hip_runtime.h>
#include <hip/hip_bf16.h>
#include <hip/hip_fp16.h>

// ---------------------------------------------------------------------------
// 3-layer GAT encoder. N=50000, E=1600000 (+N self loops), H=2 (layers 1-2),
// F=64 per head, F_IN=128.
// R1..R13: CSR counting-sort build, MFMA GEMMs, fused gather+GEMM. 337us.
// R14 FAILED: launch_bounds(256,8) gutted gather pipeline (VGPR 32).
// R15 NEUTRAL: occupancy isn't the lever; waves x per-wave-MLP saturates.
// R16: h tables fp8 e4m3 -> FETCH 165->61.5MB, gg 67->52.5us, 294us total.
// R17 NEUTRAL/NEG: shfl-cooperative meta cut VALU 55->38% but DS ops on
//      critical path; 54us. Lesson: per-edge issue cost x latency is the
//      binding product; VALU floor ~29us of gg.
// R18: 8 lanes x uint4 per node (was 16 x uint2): halves VMEM instructions
//      AND halves replicated meta-VALU per edge; same lines-in-flight
//      (depth 2+2 x 16B = 64B/lane). 32 nodes/block, GEMM 32xOUTN,
//      wave = (row-tile, head) -> no cross-wave alS add at OUTN=128.
//      gat_gather_out: 4 lanes x uint4. gemm1 fused into edge_partition
//      dispatch (independent -> overlap). 7 dispatches.
// ---------------------------------------------------------------------------

#define ELU(x) ((x) > 0.f ? (x) : (__expf(x) - 1.f))
#define BSH 8                       // 256 nodes per bucket
#define CHK 8192                    // edges per histogram/partition block

typedef _Float16 f16x8 __attribute__((ext_vector_type(8)));
typedef float    f32x4 __attribute__((ext_vector_type(4)));
typedef float    f32x2 __attribute__((ext_vector_type(2)));

// pack 4 f16 (as 2 half2) -> 4 fp8 e4m3 in one dword (RNE in HW)
__device__ inline unsigned int f16x4_to_fp8(__half2 h0, __half2 h1) {
    float2 a = __half22float2(h0), b = __half22float2(h1);
    unsigned int r = __builtin_amdgcn_cvt_pk_fp8_f32(a.x, a.y, 0, false);
    r = __builtin_amdgcn_cvt_pk_fp8_f32(b.x, b.y, r, true);
    return r;
}

// ---------------- phase0: Wt builds + per-block dst histogram rows ---------
__global__ __launch_bounds__(256) void phase0(
    const float* __restrict__ W1, __half* __restrict__ Wt1,
    const float* __restrict__ W2, __half* __restrict__ Wt2,
    const float* __restrict__ W3, __half* __restrict__ Wt3,
    const int* __restrict__ ei, int* __restrict__ bhist_rows, int E_)
{
    const int t = threadIdx.x;
    const int b = blockIdx.x;
    if (b < 160) {                                   // Wt[n][k] = (h) W[k][n]
        const float* W; __half* Wt; int N, base;
        if (b < 64)       { W = W1; Wt = Wt1; N = 128; base = b; }
        else if (b < 128) { W = W2; Wt = Wt2; N = 128; base = b - 64; }
        else              { W = W3; Wt = Wt3; N = 64;  base = b - 128; }
        int idx = base * 256 + t;
        if (idx < N * 128) {
            int nn = idx >> 7, k = idx & 127;
            Wt[idx] = __float2half(W[k * N + nn]);
        }
    } else {                                         // dst histogram row
        __shared__ int cnt[256];
        int hb = b - 160;
        cnt[t] = 0;
        __syncthreads();
        const int e0 = hb * CHK;
        for (int i = t; i < CHK; i += 256) {
            int e = e0 + i;
            if (e >= E_) break;
            atomicAdd(&cnt[ei[E_ + e] >> BSH], 1);
        }
        __syncthreads();
        bhist_rows[hb * 256 + t] = cnt[t];
    }
}

// one block per bucket: (a) bucket totals + scan (block 0 writes boff),
// (b) column scan of this bucket -> per-partition-block bases,
// (c) self-loop part entries at bucket tail. HB <= 256.
__global__ __launch_bounds__(256) void scan_bases(
    const int* __restrict__ bhist_rows, int* __restrict__ boff,
    int* __restrict__ bases, int* __restrict__ part, int HB, int n, int NB)
{
    __shared__ int tot[256];
    __shared__ int col[256];
    const int t = threadIdx.x;
    const int b = blockIdx.x;                        // bucket

    // bucket totals (+ self loops), inclusive scan
    int v = 0;
    for (int r = 0; r < HB; r++) v += bhist_rows[r * 256 + t];
    int nodes_t = n - (t << BSH);
    nodes_t = nodes_t < 0 ? 0 : (nodes_t > 256 ? 256 : nodes_t);
    v = (t < NB) ? (v + nodes_t) : 0;
    tot[t] = v;
    __syncthreads();
    for (int d = 1; d < 256; d <<= 1) {
        int x = (t >= d) ? tot[t - d] : 0;
        __syncthreads();
        tot[t] += x;
        __syncthreads();
    }
    if (b == 0) {
        if (t < NB) boff[t + 1] = tot[t];
        if (t == 0) boff[0] = 0;
    }
    const int base0 = (b > 0) ? tot[b - 1] : 0;      // boff[b]
    const int bend  = tot[b];                        // boff[b+1]

    // column scan for this bucket -> bases
    int c = (t < HB) ? bhist_rows[t * 256 + b] : 0;
    col[t] = c;
    __syncthreads();
    for (int d = 1; d < 256; d <<= 1) {
        int x = (t >= d) ? col[t - d] : 0;
        __syncthreads();
        col[t] += x;
        __syncthreads();
    }
    if (t < HB) bases[b * HB + t] = base0 + col[t] - c;   // exclusive

    // self loops at bucket tail (coalesced)
    const int n0 = b << BSH;
    const int nodes = min(256, n - n0);
    const int sl0 = bend - nodes;
    if (t < nodes) part[sl0 + t] = (n0 + t) | (t << 16);
}

// ---------------- fused: edge partition (blocks < HB) + gemm1 (rest) -------
// Both depend only on phase0/scan_bases; fusing removes a dispatch and
// overlaps gemm1 under the partition's scattered writes.
__global__ __launch_bounds__(256) void partition_gemm1(
    const int* __restrict__ ei, const int* __restrict__ bases,
    int* __restrict__ part, int E_, int HB, int NB,
    const float* __restrict__ A, const __half* __restrict__ Wt,
    unsigned char* __restrict__ Hout, const float* __restrict__ a_s,
    const float* __restrict__ a_d, float* __restrict__ alS,
    float* __restrict__ alD, int nrows)
{
    __shared__ union SM {
        struct { int cnt[256]; int sbase[256]; } p;
        struct { _Float16 wt[128 * 136]; _Float16 hst[4][16 * 136]; } g;
    } sm;
    const int t = threadIdx.x;

    if (blockIdx.x < HB) {
        // ---- edge partition: deterministic bases, LDS-local cursors ----
        const int hb = blockIdx.x;
        sm.p.cnt[t] = 0;
        sm.p.sbase[t] = (t < NB) ? bases[t * HB + hb] : 0;
        __syncthreads();
        const int e0 = hb * CHK;
        for (int i = t; i < CHK; i += 256) {
            int e = e0 + i;
            if (e >= E_) break;
            int src = ei[e], dst = ei[E_ + e];
            int b = dst >> BSH;
            int pos = sm.p.sbase[b] + atomicAdd(&sm.p.cnt[b], 1);
            part[pos] = src | ((dst & 255) << 16);
        }
        return;
    }

    // ---- layer-1 MFMA GEMM (fp32 A, in-register cvt; LDS W), fp8 out ----
    constexpr int N = 128, NT = 8, WR = 136;
    _Float16* wt = sm.g.wt;

    const int w = t >> 6, l = t & 63;
    const int q = l >> 4, nn1 = l & 15;
    const int node0 = (blockIdx.x - HB) * 64;
    const int row_base = node0 + w * 16;

    for (int i = t; i < N * 16; i += 256) {
        int r = i >> 4, c = i & 15;
        float4 v = *(const float4*)&Wt[r * 128 + c * 8];
        *(float4*)&wt[r * WR + c * 8] = v;
    }
    __syncthreads();

    f32x4 acc[NT];
#pragma unroll
    for (int ct = 0; ct < NT; ct++) acc[ct] = (f32x4){0.f, 0.f, 0.f, 0.f};

    int arow = row_base + nn1; if (arow >= nrows) arow = nrows - 1;
    const float* Ap = A + (size_t)arow * 128 + q * 8;
#pragma unroll
    for (int ks = 0; ks < 4; ks++) {
        float4 va = *(const float4*)(Ap + ks * 32);
        float4 vb = *(const float4*)(Ap + ks * 32 + 4);
        f16x8 a = { (_Float16)va.x, (_Float16)va.y, (_Float16)va.z, (_Float16)va.w,
                    (_Float16)vb.x, (_Float16)vb.y, (_Float16)vb.z, (_Float16)vb.w };
#pragma unroll
        for (int ct = 0; ct < NT; ct++) {
            f16x8 bb = *(const f16x8*)&wt[(ct * 16 + nn1) * WR + ks * 32 + q * 8];
            acc[ct] = __builtin_amdgcn_mfma_f32_16x16x32_f16(a, bb, acc[ct], 0, 0, 0);
        }
    }

    float asv[NT], adv[NT];
#pragma unroll
    for (int ct = 0; ct < NT; ct++) {
        asv[ct] = a_s[ct * 16 + nn1];
        adv[ct] = a_d[ct * 16 + nn1];
    }
#pragma unroll
    for (int r = 0; r < 4; r++) {
        int grow = row_base + q * 4 + r;
        float s0 = 0.f, d0 = 0.f, s1 = 0.f, d1 = 0.f;
#pragma unroll
        for (int ct = 0; ct < NT; ct++) {
            float v = acc[ct][r];
            float ps = v * asv[ct], pd = v * adv[ct];
            if (ct >= 4) { s1 += ps; d1 += pd; }
            else         { s0 += ps; d0 += pd; }
        }
#pragma unroll
        for (int m = 1; m < 16; m <<= 1) {
            s0 += __shfl_xor(s0, m); d0 += __shfl_xor(d0, m);
            s1 += __shfl_xor(s1, m); d1 += __shfl_xor(d1, m);
        }
        if (nn1 == 0 && grow < nrows) {
            alS[grow * 2] = s0;     alD[grow * 2] = d0;
            alS[grow * 2 + 1] = s1; alD[grow * 2 + 1] = d1;
        }
    }

#pragma unroll
    for (int ct = 0; ct < NT; ct++)
#pragma unroll
        for (int r = 0; r < 4; r++)
            sm.g.hst[w][(q * 4 + r) * WR + ct * 16 + nn1] = (_Float16)acc[ct][r];
    __syncthreads();
    {
        int row = l >> 2, c = l & 3;            // 4 lanes x 32 cols
        int grow = row_base + row;
        if (grow < nrows) {
#pragma unroll
            for (int i = 0; i < 4; i++) {
                float4 v = *(float4*)&sm.g.hst[w][row * WR + c * 32 + i * 8];
                const __half2* hp = (const __half2*)&v;
                uint2 o;
                o.x = f16x4_to_fp8(hp[0], hp[1]);
                o.y = f16x4_to_fp8(hp[2], hp[3]);
                *(uint2*)&Hout[(size_t)grow * 128 + c * 32 + i * 8] = o;
            }
        }
    }
}

// one block per bucket: per-node degree count, LDS scan -> off[], place, flush
__global__ __launch_bounds__(256) void bucket_fill(
    const int* __restrict__ boff, const int* __restrict__ part,
    int* __restrict__ csr, int* __restrict__ off, int n)
{
    __shared__ int sm[256];
    __shared__ int cur[256];
    __shared__ int slice[12544];
    const int t = threadIdx.x;
    const int b = blockIdx.x;
    const int n0 = b << BSH;
    const int nodes = min(256, n - n0);
    const int off0 = boff[b];
    const int sz = boff[b + 1] - off0;

    cur[t] = 0;
    __syncthreads();
    for (int i = t; i < sz; i += 256)
        atomicAdd(&cur[(part[off0 + i] >> 16) & 255], 1);
    __syncthreads();
    int v = cur[t];
    sm[t] = v;
    __syncthreads();
    for (int d = 1; d < 256; d <<= 1) {
        int x = (t >= d) ? sm[t - d] : 0;
        __syncthreads();
        sm[t] += x;
        __syncthreads();
    }
    const int excl = sm[t] - v;
    if (t < nodes) off[n0 + t] = off0 + excl;
    if (t == nodes - 1) off[n0 + nodes] = off0 + sz;
    cur[t] = excl;
    __syncthreads();

    if (sz <= 12544) {
        for (int i = t; i < sz; i += 256) {
            int p  = part[off0 + i];
            int dl = (p >> 16) & 255;
            int pos = atomicAdd(&cur[dl], 1);
            slice[pos] = p & 0xFFFF;
        }
        __syncthreads();
        for (int i = t; i < sz; i += 256)
            csr[off0 + i] = slice[i];
    } else {                                     // fallback (shouldn't trigger)
        for (int i = t; i < sz; i += 256) {
            int p  = part[off0 + i];
            int dl = (p >> 16) & 255;
            int pos = atomicAdd(&cur[dl], 1);
            csr[off0 + pos] = p & 0xFFFF;
        }
    }
}

// ---------------- fused gather (H=2) + next-layer GEMM (global-read W) -----
// R18: 8 lanes x uint4 per node, 32 nodes/block, depth-2+2 prefetch.
// h rows fp8, 128B. GEMM 32xOUTN: wave = (row-tile, head-half).
template<int OUTN>
__global__ __launch_bounds__(256) void gat_gather_gemm(
    const int* __restrict__ off, const int* __restrict__ csr,
    const unsigned char* __restrict__ h, const float* __restrict__ alS,
    const float* __restrict__ alD, const float* __restrict__ bias,
    const __half* __restrict__ Wt, const float* __restrict__ a_s,
    const float* __restrict__ a_d, unsigned char* __restrict__ Hout,
    float* __restrict__ alSo, float* __restrict__ alDo, int n)
{
    constexpr int HF = 128, WR = 136;     // HF in BYTES (fp8)
    constexpr int CTW = OUTN / 32;        // col-tiles per wave (128->4, 64->2)
    __shared__ _Float16 actT[32 * WR];    // act rows; reused for out staging
    __shared__ float red_s[4][16], red_d[4][16];

    const int t = threadIdx.x;
    const int node0 = blockIdx.x * 32;

    // ---- gather: 8 lanes/node, lane covers 16 fp8 cols ----
    const int l = t & 7;
    const int nl = t >> 3;                 // node-local 0..31
    const int node = node0 + nl;
    const bool valid = node < n;
    const int c0 = l * 16;                 // byte & col offset (1B/col)
    const int head = l >> 2;
    const int nodec = valid ? node : (n - 1);
    const float ad = alD[nodec * 2 + head];
    int s0 = 0, s1 = 1;
    if (valid) { s0 = off[node]; s1 = off[node + 1]; }
    const int last = s1 - 1;

    float a[16];
#pragma unroll
    for (int i = 0; i < 16; i++) a[i] = 0.f;
    float wsum = 0.f;

    float as[2]; uint4 v[2];
    {
        int srcs[2];
#pragma unroll
        for (int k = 0; k < 2; k++) {
            int j = s0 + k;
            srcs[k] = csr[j <= last ? j : last];
        }
#pragma unroll
        for (int k = 0; k < 2; k++) {
            as[k] = alS[srcs[k] * 2 + head];
            v[k]  = *(const uint4*)&h[(size_t)srcs[k] * HF + c0];
        }
    }
    for (int j = s0; j < s1; j += 2) {
        int nsrc[2];
#pragma unroll
        for (int k = 0; k < 2; k++) {
            int jj = j + 2 + k;
            nsrc[k] = csr[jj <= last ? jj : last];
        }
        float nas[2]; uint4 nv[2];
#pragma unroll
        for (int k = 0; k < 2; k++) {
            nas[k] = alS[nsrc[k] * 2 + head];
            nv[k]  = *(const uint4*)&h[(size_t)nsrc[k] * HF + c0];
        }
#pragma unroll
        for (int k = 0; k < 2; k++) {
            float s = as[k] + ad;
            s = s > 0.f ? s : 0.2f * s;     // leaky_relu(0.2)
            float w = __expf(s);
            w = (j + k <= last) ? w : 0.f;
            unsigned int dw[4] = { v[k].x, v[k].y, v[k].z, v[k].w };
#pragma unroll
            for (int d = 0; d < 4; d++) {
                f32x2 lo = __builtin_amdgcn_cvt_pk_f32_fp8(dw[d], false);
                f32x2 hi = __builtin_amdgcn_cvt_pk_f32_fp8(dw[d], true);
                a[d * 4 + 0] = fmaf(w, lo.x, a[d * 4 + 0]);
                a[d * 4 + 1] = fmaf(w, lo.y, a[d * 4 + 1]);
                a[d * 4 + 2] = fmaf(w, hi.x, a[d * 4 + 2]);
                a[d * 4 + 3] = fmaf(w, hi.y, a[d * 4 + 3]);
            }
            wsum += w;
        }
#pragma unroll
        for (int k = 0; k < 2; k++) { as[k] = nas[k]; v[k] = nv[k]; }
    }
    {
        const float inv = 1.f / (wsum + 1e-16f);
        float bb[16];
        *(float4*)&bb[0]  = *(const float4*)&bias[c0];
        *(float4*)&bb[4]  = *(const float4*)&bias[c0 + 4];
        *(float4*)&bb[8]  = *(const float4*)&bias[c0 + 8];
        *(float4*)&bb[12] = *(const float4*)&bias[c0 + 12];
        __half2 p[8];
#pragma unroll
        for (int i = 0; i < 8; i++) {
            float o0 = ELU(fmaf(a[2 * i],     inv, bb[2 * i]));
            float o1 = ELU(fmaf(a[2 * i + 1], inv, bb[2 * i + 1]));
            p[i] = __floats2half2_rn(o0, o1);
        }
        *(float4*)&actT[nl * WR + c0]     = *(float4*)&p[0];
        *(float4*)&actT[nl * WR + c0 + 8] = *(float4*)&p[4];
    }
    __syncthreads();

    // ---- GEMM: D[32 rows][OUTN cols] = act @ Wt^T, B from global Wt ----
    const int w = t >> 6, l64 = t & 63, q = l64 >> 4, nn = l64 & 15;
    const int rt = w & 1;                  // row-tile (16 rows)
    const int ch = w >> 1;                 // col half (head for OUTN=128)
    const int rbase = rt * 16;
    const int cbase = ch * (OUTN / 2);
    const __half* Wp = Wt + (size_t)(cbase + nn) * 128 + q * 8;
    f32x4 acc[CTW];
#pragma unroll
    for (int ct = 0; ct < CTW; ct++) acc[ct] = (f32x4){0.f, 0.f, 0.f, 0.f};
#pragma unroll
    for (int ks = 0; ks < 4; ks++) {
        f16x8 af = *(const f16x8*)&actT[(rbase + nn) * WR + ks * 32 + q * 8];
#pragma unroll
        for (int ct = 0; ct < CTW; ct++) {
            f16x8 bb = *(const f16x8*)(Wp + ct * 16 * 128 + ks * 32);
            acc[ct] = __builtin_amdgcn_mfma_f32_16x16x32_f16(af, bb, acc[ct], 0, 0, 0);
        }
    }

    // alS/alD partials over this wave's cols (full head at OUTN=128)
    float asv[CTW], adv2[CTW];
#pragma unroll
    for (int ct = 0; ct < CTW; ct++) {
        asv[ct]  = a_s[cbase + ct * 16 + nn];
        adv2[ct] = a_d[cbase + ct * 16 + nn];
    }
#pragma unroll
    for (int r = 0; r < 4; r++) {
        float s = 0.f, d = 0.f;
#pragma unroll
        for (int ct = 0; ct < CTW; ct++) {
            float vv = acc[ct][r];
            s = fmaf(vv, asv[ct], s);
            d = fmaf(vv, adv2[ct], d);
        }
#pragma unroll
        for (int m = 1; m < 16; m <<= 1) {
            s += __shfl_xor(s, m);
            d += __shfl_xor(d, m);
        }
        if (nn == 0) { red_s[w][q * 4 + r] = s; red_d[w][q * 4 + r] = d; }
    }
    __syncthreads();        // all A-frag reads done -> safe to overwrite actT

    // stage output into actT (reuse)
#pragma unroll
    for (int ct = 0; ct < CTW; ct++)
#pragma unroll
        for (int r = 0; r < 4; r++)
            actT[(rbase + q * 4 + r) * WR + cbase + ct * 16 + nn] = (_Float16)acc[ct][r];

    // alSo/alDo
    if (OUTN == 128) {
        if (t < 64) {                      // wave ww covers (rt=ww&1, head=ww>>1)
            int i = t & 15, ww = t >> 4;
            int grow = node0 + (ww & 1) * 16 + i;
            if (grow < n) {
                alSo[grow * 2 + (ww >> 1)] = red_s[ww][i];
                alDo[grow * 2 + (ww >> 1)] = red_d[ww][i];
            }
        }
    } else {
        if (t < 32) {                      // sum the two col-halves
            int i = t & 15, rt2 = t >> 4;
            int grow = node0 + rt2 * 16 + i;
            if (grow < n) {
                alSo[grow] = red_s[rt2][i] + red_s[rt2 + 2][i];
                alDo[grow] = red_d[rt2][i] + red_d[rt2 + 2][i];
            }
        }
    }
    __syncthreads();

    // coalesced Hout store (fp8)
    if (OUTN == 128) {
        int row = t >> 3, c = t & 7;       // 8 lanes x 16B
        int grow = node0 + row;
        if (grow < n) {
            float4 p0 = *(float4*)&actT[row * WR + c * 16];
            float4 p1 = *(float4*)&actT[row * WR + c * 16 + 8];
            const __half2* h0 = (const __half2*)&p0;
            const __half2* h1 = (const __half2*)&p1;
            uint4 o;
            o.x = f16x4_to_fp8(h0[0], h0[1]);
            o.y = f16x4_to_fp8(h0[2], h0[3]);
            o.z = f16x4_to_fp8(h1[0], h1[1]);
            o.w = f16x4_to_fp8(h1[2], h1[3]);
            *(uint4*)&Hout[(size_t)grow * 128 + c * 16] = o;
        }
    } else {
        int row = t >> 3, c = t & 7;       // 8 lanes x 8B
        int grow = node0 + row;
        if (grow < n) {
            float4 p0 = *(float4*)&actT[row * WR + c * 8];
            const __half2* hp = (const __half2*)&p0;
            uint2 o;
            o.x = f16x4_to_fp8(hp[0], hp[1]);
            o.y = f16x4_to_fp8(hp[2], hp[3]);
            *(uint2*)&Hout[(size_t)grow * 64 + c * 8] = o;
        }
    }
}

// ---------------- final gather (H=1, fp8 h) -> fp32 out --------------------
// R18: 4 lanes x uint4 per node, 64 nodes/block, depth-2+2 prefetch.
__global__ __launch_bounds__(256) void gat_gather_out(
    const int* __restrict__ off, const int* __restrict__ csr,
    const unsigned char* __restrict__ h, const float* __restrict__ alS,
    const float* __restrict__ alD, const float* __restrict__ b,
    float* __restrict__ out, int n)
{
    constexpr int HF = 64;                 // bytes per row (fp8)
    const int l    = threadIdx.x & 3;
    const int node = blockIdx.x * 64 + (threadIdx.x >> 2);
    if (node >= n) return;
    const int c0   = l * 16;
    const float ad = alD[node];

    const int s0 = off[node], s1 = off[node + 1];
    const int last = s1 - 1;

    float a[16];
#pragma unroll
    for (int i = 0; i < 16; i++) a[i] = 0.f;
    float wsum = 0.f;

    float as[2]; uint4 v[2];
    {
        int srcs[2];
#pragma unroll
        for (int k = 0; k < 2; k++) {
            int j = s0 + k;
            srcs[k] = csr[j <= last ? j : last];
        }
#pragma unroll
        for (int k = 0; k < 2; k++) {
            as[k] = alS[srcs[k]];
            v[k]  = *(const uint4*)&h[(size_t)srcs[k] * HF + c0];
        }
    }
    for (int j = s0; j < s1; j += 2) {
        int nsrc[2];
#pragma unroll
        for (int k = 0; k < 2; k++) {
            int jj = j + 2 + k;
            nsrc[k] = csr[jj <= last ? jj : last];
        }
        float nas[2]; uint4 nv[2];
#pragma unroll
        for (int k = 0; k < 2; k++) {
            nas[k] = alS[nsrc[k]];
            nv[k]  = *(const uint4*)&h[(size_t)nsrc[k] * HF + c0];
        }
#pragma unroll
        for (int k = 0; k < 2; k++) {
            float s = as[k] + ad;
            s = s > 0.f ? s : 0.2f * s;
            float w = __expf(s);
            w = (j + k <= last) ? w : 0.f;
            unsigned int dw[4] = { v[k].x, v[k].y, v[k].z, v[k].w };
#pragma unroll
            for (int d = 0; d < 4; d++) {
                f32x2 lo = __builtin_amdgcn_cvt_pk_f32_fp8(dw[d], false);
                f32x2 hi = __builtin_amdgcn_cvt_pk_f32_fp8(dw[d], true);
                a[d * 4 + 0] = fmaf(w, lo.x, a[d * 4 + 0]);
                a[d * 4 + 1] = fmaf(w, lo.y, a[d * 4 + 1]);
                a[d * 4 + 2] = fmaf(w, hi.x, a[d * 4 + 2]);
                a[d * 4 + 3] = fmaf(w, hi.y, a[d * 4 + 3]);
            }
            wsum += w;
        }
#pragma unroll
        for (int k = 0; k < 2; k++) { as[k] = nas[k]; v[k] = nv[k]; }
    }

    const float inv = 1.f / (wsum + 1e-16f);
    float bb[16];
    *(float4*)&bb[0]  = *(const float4*)&b[c0];
    *(float4*)&bb[4]  = *(const float4*)&b[c0 + 4];
    *(float4*)&bb[8]  = *(const float4*)&b[c0 + 8];
    *(float4*)&bb[12] = *(const float4*)&b[c0 + 12];
    float4 o[4];
#pragma unroll
    for (int g = 0; g < 4; g++) {
        o[g].x = ELU(fmaf(a[4 * g + 0], inv, bb[4 * g + 0]));
        o[g].y = ELU(fmaf(a[4 * g + 1], inv, bb[4 * g + 1]));
        o[g].z = ELU(fmaf(a[4 * g + 2], inv, bb[4 * g + 2]));
        o[g].w = ELU(fmaf(a[4 * g + 3], inv, bb[4 * g + 3]));
    }
#pragma unroll
    for (int g = 0; g < 4; g++)
        *(float4*)&out[(size_t)node * HF + c0 + 4 * g] = o[g];
}

extern "C" void kernel_launch(void* const* d_in, const int* in_sizes, int n_in,
                              void* d_out, int out_size, void* d_ws, size_t ws_size,
                              hipStream_t stream)
{
    const float* x   = (const float*)d_in[0];
    const float* W1  = (const float*)d_in[1];
    const float* as1 = (const float*)d_in[2];
    const float* ad1 = (const float*)d_in[3];
    const float* b1  = (const float*)d_in[4];
    const float* W2  = (const float*)d_in[5];
    const float* as2 = (const float*)d_in[6];
    const float* ad2 = (const float*)d_in[7];
    const float* b2  = (const float*)d_in[8];
    const float* W3  = (const float*)d_in[9];
    const float* as3 = (const float*)d_in[10];
    const float* ad3 = (const float*)d_in[11];
    const float* b3  = (const float*)d_in[12];
    const int*   ei  = (const int*)d_in[13];
    float* out = (float*)d_out;

    const int N_   = in_sizes[0] / 128;     // 50000
    const int E_   = in_sizes[13] / 2;      // 1600000
    const int Etot = E_ + N_;
    const int NB   = (N_ + 255) >> BSH;     // 196 buckets
    const int HB   = (E_ + CHK - 1) / CHK;  // 196 hist/partition blocks

    char* ws = (char*)d_ws;
    size_t o = 0;
    auto alloc = [&](size_t bytes) { void* p = ws + o; o += (bytes + 255) & ~255ull; return p; };
    unsigned char* h1 = (unsigned char*)alloc((size_t)N_ * 128);
    unsigned char* h2 = (unsigned char*)alloc((size_t)N_ * 128);
    unsigned char* h3 = (unsigned char*)alloc((size_t)N_ * 64);
    __half* Wt1   = (__half*)alloc((size_t)128 * 128 * 2);
    __half* Wt2   = (__half*)alloc((size_t)128 * 128 * 2);
    __half* Wt3   = (__half*)alloc((size_t)64 * 128 * 2);
    float* alSa   = (float*)alloc((size_t)N_ * 2 * 4);
    float* alDa   = (float*)alloc((size_t)N_ * 2 * 4);
    float* alSb   = (float*)alloc((size_t)N_ * 2 * 4);
    float* alDb   = (float*)alloc((size_t)N_ * 2 * 4);
    int*   offb   = (int*)alloc((size_t)(N_ + 1) * 4);
    int*   bhrows = (int*)alloc((size_t)HB * 256 * 4);
    int*   boff   = (int*)alloc((size_t)257 * 4);
    int*   bases  = (int*)alloc((size_t)256 * HB * 4);
    int*   part   = (int*)alloc((size_t)Etot * 4);
    int*   csr    = (int*)alloc((size_t)Etot * 4);

    const dim3 blk(256);
    const int G1 = (N_ + 63) / 64;          // gemm1 blocks

    // ---- phase0 + CSR build (no global atomics anywhere) ----
    phase0<<<160 + HB, blk, 0, stream>>>(W1, Wt1, W2, Wt2, W3, Wt3, ei, bhrows, E_);
    scan_bases<<<NB, blk, 0, stream>>>(bhrows, boff, bases, part, HB, N_, NB);
    partition_gemm1<<<HB + G1, blk, 0, stream>>>(
        ei, bases, part, E_, HB, NB,
        x, Wt1, h1, as1, ad1, alSa, alDa, N_);
    bucket_fill<<<NB, blk, 0, stream>>>(boff, part, csr, offb, N_);

    // ---- layer pipeline ----
    gat_gather_gemm<128><<<(N_ + 31) / 32, blk, 0, stream>>>(
        offb, csr, h1, alSa, alDa, b1, Wt2, as2, ad2, h2, alSb, alDb, N_);
    gat_gather_gemm<64><<<(N_ + 31) / 32, blk, 0, stream>>>(
        offb, csr, h2, alSb, alDb, b2, Wt3, as3, ad3, h3, alSa, alDa, N_);
    gat_gather_out<<<(N_ + 63) / 64, blk, 0, stream>>>(
        offb, csr, h3, alSa, alDa, b3, out, N_);
}